// Round 1
// 2595.955 us; speedup vs baseline: 1.1574x; 1.1574x over previous
//
#include <hip/hip_runtime.h>
#include <math.h>

#define SEQ   2048
#define BATCH 128
#define HID   256

// One block per batch row; 512 threads = 8 waves.
// Wave w owns output rows j in [w*32, w*32+32).
// lane = jg*8 + kg: jg = lane>>3 picks 4 rows j0 = w*32+jg*4 .. +3,
//                   kg = lane&7  picks k-chunk [kg*32, kg*32+32).
// Each lane: 128 weights in VGPRs, reads only ITS 128 B of h per step
// (8x ds_read_b128, XOR-rotated layout -> all 32 banks hit exactly once,
// 8-way same-address broadcast across jg lanes), 128 FMAs, then the 8
// kg-partials per row are combined with 4 shfl_xor. One barrier per step.
// y-projection fused: per-wave partial -> LDS (double-buffered), finalized
// by a rotating wave one step later. No second kernel.

__global__ __launch_bounds__(512, 2) void rnn_kernel(
    const float* __restrict__ x,      // (SEQ, BATCH)
    const float* __restrict__ h0,     // (BATCH, HID)
    const float* __restrict__ noise,  // (SEQ, BATCH, HID)
    const float* __restrict__ W_ih,   // (HID, 1)
    const float* __restrict__ W_hh,   // (HID, HID)
    const float* __restrict__ W_hhb,  // (HID, HID)
    const float* __restrict__ b_h,    // (HID)
    const float* __restrict__ Wy,     // (OUT, HID) -> row 0
    const float* __restrict__ by,     // (OUT)
    const int*   __restrict__ ctx,    // scalar
    float* __restrict__ h_out,        // (BATCH, SEQ, HID)
    float* __restrict__ y_out)        // (BATCH, SEQ)
{
    const int b    = blockIdx.x;
    const int tid  = threadIdx.x;
    const int w    = tid >> 6;
    const int lane = tid & 63;
    const int jg   = lane >> 3;
    const int kg   = lane & 7;
    const int j0   = w * 32 + jg * 4;
    const int jres = j0 + (kg & 3);    // the row this lane holds after reduce

    __shared__ __align__(16) float hbuf[2][HID];
    __shared__ float ywave[2][8];

    int iv = *ctx;
    float c = (iv > 1000000 || iv < -1000000) ? __int_as_float(iv) : (float)iv;

    // One-time: W_eff slice (4 rows x 32 cols) into registers.
    float wreg[4][32];
    #pragma unroll
    for (int e = 0; e < 4; ++e) {
        const float4* wr  = (const float4*)&W_hh [(j0 + e) * HID + kg * 32];
        const float4* wrb = (const float4*)&W_hhb[(j0 + e) * HID + kg * 32];
        #pragma unroll
        for (int q = 0; q < 8; ++q) {
            float4 av = wr[q], bv = wrb[q];
            wreg[e][4*q+0] = av.x + c * bv.x;
            wreg[e][4*q+1] = av.y + c * bv.y;
            wreg[e][4*q+2] = av.z + c * bv.z;
            wreg[e][4*q+3] = av.w + c * bv.w;
        }
    }

    const float win = W_ih[jres];
    const float bh  = b_h[jres];
    const float w0  = Wy[jres];        // row 0 of W
    const float b0v = by[0];

    // Initial h, stored swizzled: logical j = (c,i,e) -> group (i+c)&7.
    if (tid < HID) {
        int cc = tid >> 5, ii = (tid >> 2) & 7, ee = tid & 3;
        hbuf[0][cc * 32 + (((ii + cc) & 7) << 2) + ee] = h0[b * HID + tid];
    }

    // Per-read LDS byte offsets: instruction i reads logical group i of
    // chunk kg at physical group (i+kg)&7 -> per-instr bank-quad disjoint.
    int voff[8];
    #pragma unroll
    for (int i = 0; i < 8; ++i)
        voff[i] = kg * 128 + (((i + kg) & 7) << 4);

    const int  b0k = kg & 1;
    const int  b1k = (kg >> 1) & 1;
    const bool wr4 = (kg < 4);
    const int  wslot = w * 32 + (((jg + w) & 7) << 2) + kg;  // swizzled write pos

    // Prefetch t=0 inputs; incremental pointers for t+1 prefetch.
    float x_next = x[b];
    float n_next = noise[(size_t)b * HID + jres];
    const float* xp = x + BATCH + b;                        // x[1][b]
    const float* np = noise + ((size_t)BATCH + b) * HID + jres;  // noise[1][b][jres]

    float* hop = h_out + (size_t)b * SEQ * HID;
    float* yp  = y_out + (size_t)b * SEQ;

    __syncthreads();

#define STEP(T, CUR)                                                         \
  {                                                                          \
    const float x_t = x_next;                                                \
    const float n_t = n_next;                                                \
    x_next = *xp;                                                            \
    n_next = *np;                                                            \
    if ((T) + 2 < SEQ) { xp += BATCH; np += (size_t)BATCH * HID; }           \
    const char* hb = (const char*)&hbuf[CUR][0];                             \
    float p0 = 0.f, p1 = 0.f, p2 = 0.f, p3 = 0.f;                            \
    _Pragma("unroll")                                                        \
    for (int i = 0; i < 8; ++i) {                                            \
      float4 h4 = *(const float4*)(hb + voff[i]);                            \
      p0 = fmaf(h4.x, wreg[0][4*i+0], p0);                                   \
      p0 = fmaf(h4.y, wreg[0][4*i+1], p0);                                   \
      p0 = fmaf(h4.z, wreg[0][4*i+2], p0);                                   \
      p0 = fmaf(h4.w, wreg[0][4*i+3], p0);                                   \
      p1 = fmaf(h4.x, wreg[1][4*i+0], p1);                                   \
      p1 = fmaf(h4.y, wreg[1][4*i+1], p1);                                   \
      p1 = fmaf(h4.z, wreg[1][4*i+2], p1);                                   \
      p1 = fmaf(h4.w, wreg[1][4*i+3], p1);                                   \
      p2 = fmaf(h4.x, wreg[2][4*i+0], p2);                                   \
      p2 = fmaf(h4.y, wreg[2][4*i+1], p2);                                   \
      p2 = fmaf(h4.z, wreg[2][4*i+2], p2);                                   \
      p2 = fmaf(h4.w, wreg[2][4*i+3], p2);                                   \
      p3 = fmaf(h4.x, wreg[3][4*i+0], p3);                                   \
      p3 = fmaf(h4.y, wreg[3][4*i+1], p3);                                   \
      p3 = fmaf(h4.z, wreg[3][4*i+2], p3);                                   \
      p3 = fmaf(h4.w, wreg[3][4*i+3], p3);                                   \
    }                                                                        \
    /* finalize y[T-1] on a rotating wave (reads other buffer: race-free) */ \
    if (w == ((T) & 7) && (T) > 0) {                                         \
      float s = (lane < 8) ? ywave[(CUR) ^ 1][lane] : 0.f;                   \
      s += __shfl_xor(s, 1, 64);                                             \
      s += __shfl_xor(s, 2, 64);                                             \
      s += __shfl_xor(s, 4, 64);                                             \
      if (lane == 0) yp[(T) - 1] = 1.f / (1.f + __expf(-(s + b0v)));         \
    }                                                                        \
    /* combine 8 kg-partials: keep the half matching my kg bit each stage */ \
    float m0 = b0k ? p1 : p0,  s0 = b0k ? p0 : p1;                           \
    float m1 = b0k ? p3 : p2,  s1 = b0k ? p2 : p3;                           \
    float q0 = m0 + __shfl_xor(s0, 1, 64);                                   \
    float q1 = m1 + __shfl_xor(s1, 1, 64);                                   \
    float mm = b1k ? q1 : q0,  ss = b1k ? q0 : q1;                           \
    float r  = mm + __shfl_xor(ss, 2, 64);                                   \
    r += __shfl_xor(r, 4, 64);                                               \
    float z  = fmaf(x_t, win, r) + bh;                                       \
    float ex = __expf(2.f * z);          /* tanh(z) = 1 - 2/(e^{2z}+1) */    \
    float hn = 1.f - 2.f / (ex + 1.f) + n_t;                                 \
    if (wr4) {                                                               \
      hbuf[(CUR) ^ 1][wslot] = hn;       /* swizzled, 32 banks, no conflict */\
      hop[jres] = hn;                                                        \
    }                                                                        \
    /* fused y projection: per-wave partial sum */                           \
    float qy = wr4 ? hn * w0 : 0.f;                                          \
    qy += __shfl_xor(qy, 1, 64);                                             \
    qy += __shfl_xor(qy, 2, 64);                                             \
    qy += __shfl_xor(qy, 4, 64);                                             \
    qy += __shfl_xor(qy, 8, 64);                                             \
    qy += __shfl_xor(qy, 16, 64);                                            \
    qy += __shfl_xor(qy, 32, 64);                                            \
    if (lane == 0) ywave[CUR][w] = qy;                                       \
    hop += HID;                                                              \
    __syncthreads();                                                         \
  }

    for (int t = 0; t < SEQ; t += 2) {
        STEP(t, 0)
        STEP(t + 1, 1)
    }

    // last y: partials for t=SEQ-1 sit in ywave[1]; loop ended on a barrier.
    if (w == 0) {
        float s = (lane < 8) ? ywave[1][lane] : 0.f;
        s += __shfl_xor(s, 1, 64);
        s += __shfl_xor(s, 2, 64);
        s += __shfl_xor(s, 4, 64);
        if (lane == 0) yp[SEQ - 1] = 1.f / (1.f + __expf(-(s + b0v)));
    }
#undef STEP
}

extern "C" void kernel_launch(void* const* d_in, const int* in_sizes, int n_in,
                              void* d_out, int out_size, void* d_ws, size_t ws_size,
                              hipStream_t stream) {
    const float* x     = (const float*)d_in[0];
    const float* h0    = (const float*)d_in[1];
    const float* noise = (const float*)d_in[2];
    const float* W_ih  = (const float*)d_in[3];
    const float* W_hh  = (const float*)d_in[4];
    const float* W_hhb = (const float*)d_in[5];
    const float* b_h   = (const float*)d_in[6];
    const float* W     = (const float*)d_in[7];
    const float* bvec  = (const float*)d_in[8];
    const int*   ctx   = (const int*)d_in[9];

    float* y_out = (float*)d_out;                         // (BATCH, SEQ)
    float* h_out = (float*)d_out + (size_t)BATCH * SEQ;   // (BATCH, SEQ, HID)

    rnn_kernel<<<dim3(BATCH), dim3(512), 0, stream>>>(
        x, h0, noise, W_ih, W_hh, W_hhb, b_h, W, bvec, ctx, h_out, y_out);
}

// Round 2
// 2231.133 us; speedup vs baseline: 1.3466x; 1.1635x over previous
//
#include <hip/hip_runtime.h>
#include <math.h>

#define SEQ   2048
#define BATCH 128
#define HID   256

// DPP cross-lane exchange (VALU, ~4-8 cyc latency vs ~100+ for DS-based shfl).
#define DPP_XOR1  0xB1   // quad_perm [1,0,3,2]  : lane ^ 1
#define DPP_XOR2  0x4E   // quad_perm [2,3,0,1]  : lane ^ 2
#define DPP_XOR7  0x141  // row_half_mirror      : lane ^ 7
#define DPP_XOR15 0x140  // row_mirror           : lane ^ 15
template<int CTRL>
__device__ __forceinline__ float dppf(float v) {
    return __builtin_bit_cast(float, __builtin_amdgcn_update_dpp(
        0, __builtin_bit_cast(int, v), CTRL, 0xF, 0xF, true));
}

// Barrier that does NOT drain vmcnt: LDS-visibility only (lgkmcnt), so the
// noise/x prefetch loads and h_out/y stores stay in flight across steps.
// (Guide 8-phase pattern: each wave drains its own LDS ops, then s_barrier.)
#define BARRIER() do { asm volatile("s_waitcnt lgkmcnt(0)" ::: "memory"); \
                       __builtin_amdgcn_s_barrier(); } while (0)

// One block per batch row; 512 threads = 8 waves.
// Wave w owns rows [w*32, w*32+32); lane = jg*8+kg: jg = lane>>3 -> 4 rows
// j0 = w*32+jg*4..+3, kg = lane&7 -> k-chunk [kg*32, kg*32+32).
// Per step: 8x ds_read_b128 (XOR-rotated layout, conflict-free), 128 FMAs,
// reduce over kg entirely in DPP (masks 7,1,2: plain xor7 then keep-half
// xor1/xor2 -> lane kg ends with row j0+(kg&3)). y-projection reduced with
// DPP (xor1,2,7,15) to 4 partials/wave in LDS, finalized by a rotating wave
// one step later (1 ds_read_b128 + 3 DPP adds). One lgkm-only barrier/step.
__global__ __launch_bounds__(512, 2) void rnn_kernel(
    const float* __restrict__ x,      // (SEQ, BATCH)
    const float* __restrict__ h0,     // (BATCH, HID)
    const float* __restrict__ noise,  // (SEQ, BATCH, HID)
    const float* __restrict__ W_ih,   // (HID, 1)
    const float* __restrict__ W_hh,   // (HID, HID)
    const float* __restrict__ W_hhb,  // (HID, HID)
    const float* __restrict__ b_h,    // (HID)
    const float* __restrict__ Wy,     // (OUT, HID) -> row 0
    const float* __restrict__ by,     // (OUT)
    const int*   __restrict__ ctx,    // scalar
    float* __restrict__ h_out,        // (BATCH, SEQ, HID)
    float* __restrict__ y_out)        // (BATCH, SEQ)
{
    const int b    = blockIdx.x;
    const int tid  = threadIdx.x;
    const int w    = tid >> 6;
    const int lane = tid & 63;
    const int jg   = lane >> 3;
    const int kg   = lane & 7;
    const int j0   = w * 32 + jg * 4;
    const int jres = j0 + (kg & 3);    // the row this lane holds after reduce

    __shared__ __align__(16) float hbuf[2][HID];
    __shared__ __align__(16) float ywave[2][32];

    int iv = *ctx;
    float c = (iv > 1000000 || iv < -1000000) ? __int_as_float(iv) : (float)iv;

    // One-time: W_eff slice (4 rows x 32 cols) into registers.
    float wreg[4][32];
    #pragma unroll
    for (int e = 0; e < 4; ++e) {
        const float4* wr  = (const float4*)&W_hh [(j0 + e) * HID + kg * 32];
        const float4* wrb = (const float4*)&W_hhb[(j0 + e) * HID + kg * 32];
        #pragma unroll
        for (int q = 0; q < 8; ++q) {
            float4 av = wr[q], bv = wrb[q];
            wreg[e][4*q+0] = av.x + c * bv.x;
            wreg[e][4*q+1] = av.y + c * bv.y;
            wreg[e][4*q+2] = av.z + c * bv.z;
            wreg[e][4*q+3] = av.w + c * bv.w;
        }
    }

    const float win = W_ih[jres];
    const float bh  = b_h[jres];
    const float w0  = Wy[jres];        // row 0 of W
    const float b0v = by[0];

    // Initial h, stored swizzled: logical j = (c,i,e) -> group (i+c)&7.
    if (tid < HID) {
        int cc = tid >> 5, ii = (tid >> 2) & 7, ee = tid & 3;
        hbuf[0][cc * 32 + (((ii + cc) & 7) << 2) + ee] = h0[b * HID + tid];
    }

    // Per-read LDS byte offsets: instruction i reads logical group i of
    // chunk kg at physical group (i+kg)&7 -> per-instr bank-quad disjoint.
    int voff[8];
    #pragma unroll
    for (int i = 0; i < 8; ++i)
        voff[i] = kg * 128 + (((i + kg) & 7) << 4);

    const int  b0k = kg & 1;
    const int  b1k = (kg >> 1) & 1;
    const bool wr4 = (kg < 4);
    const int  wslot = w * 32 + (((jg + w) & 7) << 2) + kg;  // swizzled write pos

    // Depth-2 prefetch: ~2 steps of slack covers a worst-case HBM miss.
    float x_next  = x[b];
    float n_next  = noise[(size_t)b * HID + jres];
    float x_next2 = x[BATCH + b];
    float n_next2 = noise[((size_t)BATCH + b) * HID + jres];
    const float* xp = x + 2 * BATCH + b;                            // x[2][b]
    const float* np = noise + ((size_t)2 * BATCH + b) * HID + jres; // noise[2][b][jres]

    float* hop = h_out + (size_t)b * SEQ * HID;
    float* yp  = y_out + (size_t)b * SEQ;

    __syncthreads();

#define STEP(T, CUR)                                                         \
  {                                                                          \
    const float x_t = x_next;                                                \
    const float n_t = n_next;                                                \
    x_next = x_next2;  n_next = n_next2;                                     \
    x_next2 = *xp;     n_next2 = *np;                                        \
    if ((T) + 3 < SEQ) { xp += BATCH; np += (size_t)BATCH * HID; }           \
    const char* hb = (const char*)&hbuf[CUR][0];                             \
    float p0 = 0.f, p1 = 0.f, p2 = 0.f, p3 = 0.f;                            \
    _Pragma("unroll")                                                        \
    for (int i = 0; i < 8; ++i) {                                            \
      float4 h4 = *(const float4*)(hb + voff[i]);                            \
      p0 = fmaf(h4.x, wreg[0][4*i+0], p0);                                   \
      p0 = fmaf(h4.y, wreg[0][4*i+1], p0);                                   \
      p0 = fmaf(h4.z, wreg[0][4*i+2], p0);                                   \
      p0 = fmaf(h4.w, wreg[0][4*i+3], p0);                                   \
      p1 = fmaf(h4.x, wreg[1][4*i+0], p1);                                   \
      p1 = fmaf(h4.y, wreg[1][4*i+1], p1);                                   \
      p1 = fmaf(h4.z, wreg[1][4*i+2], p1);                                   \
      p1 = fmaf(h4.w, wreg[1][4*i+3], p1);                                   \
      p2 = fmaf(h4.x, wreg[2][4*i+0], p2);                                   \
      p2 = fmaf(h4.y, wreg[2][4*i+1], p2);                                   \
      p2 = fmaf(h4.z, wreg[2][4*i+2], p2);                                   \
      p2 = fmaf(h4.w, wreg[2][4*i+3], p2);                                   \
      p3 = fmaf(h4.x, wreg[3][4*i+0], p3);                                   \
      p3 = fmaf(h4.y, wreg[3][4*i+1], p3);                                   \
      p3 = fmaf(h4.z, wreg[3][4*i+2], p3);                                   \
      p3 = fmaf(h4.w, wreg[3][4*i+3], p3);                                   \
    }                                                                        \
    /* finalize y[T-1] on a rotating wave (reads other buffer: race-free) */ \
    if (w == ((T) & 7) && (T) > 0) {                                         \
      float4 yv = *(const float4*)&ywave[(CUR) ^ 1][(lane & 7) * 4];         \
      float s = (yv.x + yv.y) + (yv.z + yv.w);                               \
      s += dppf<DPP_XOR1>(s);                                                \
      s += dppf<DPP_XOR2>(s);                                                \
      s += dppf<DPP_XOR7>(s);                                                \
      if (lane == 0) yp[(T) - 1] = 1.f / (1.f + __expf(-(s + b0v)));         \
    }                                                                        \
    /* reduce over kg: plain xor7 (row_half_mirror), then keep-half xor1,  */\
    /* keep-half xor2 -> lane kg holds row j0+(kg&3). All DPP, no DS ops.  */\
    p0 += dppf<DPP_XOR7>(p0);                                                \
    p1 += dppf<DPP_XOR7>(p1);                                                \
    p2 += dppf<DPP_XOR7>(p2);                                                \
    p3 += dppf<DPP_XOR7>(p3);                                                \
    float m0 = b0k ? p1 : p0,  s0 = b0k ? p0 : p1;                           \
    float m1 = b0k ? p3 : p2,  s1 = b0k ? p2 : p3;                           \
    float q0 = m0 + dppf<DPP_XOR1>(s0);                                      \
    float q1 = m1 + dppf<DPP_XOR1>(s1);                                      \
    float mm = b1k ? q1 : q0,  ss = b1k ? q0 : q1;                           \
    float r  = mm + dppf<DPP_XOR2>(ss);                                      \
    float z  = fmaf(x_t, win, r) + bh;                                       \
    float ex = __expf(2.f * z);          /* tanh(z) = 1 - 2/(e^{2z}+1) */    \
    float hn = 1.f - 2.f / (ex + 1.f) + n_t;                                 \
    if (wr4) {                                                               \
      hbuf[(CUR) ^ 1][wslot] = hn;       /* swizzled, 32 banks, no conflict */\
      hop[jres] = hn;                                                        \
    }                                                                        \
    /* fused y projection: DPP-reduce to 16-lane-group sums, 4 floats/wave */\
    float qy = wr4 ? hn * w0 : 0.f;                                          \
    qy += dppf<DPP_XOR1>(qy);                                                \
    qy += dppf<DPP_XOR2>(qy);                                                \
    qy += dppf<DPP_XOR7>(qy);                                                \
    qy += dppf<DPP_XOR15>(qy);                                               \
    if ((lane & 15) == 0) ywave[CUR][w * 4 + (lane >> 4)] = qy;              \
    hop += HID;                                                              \
    BARRIER();                                                               \
  }

    for (int t = 0; t < SEQ; t += 2) {
        STEP(t, 0)
        STEP(t + 1, 1)
    }

    // last y: partials for t=SEQ-1 sit in ywave[1]; loop ended on a barrier.
    if (w == 0) {
        float4 yv = *(const float4*)&ywave[1][(lane & 7) * 4];
        float s = (yv.x + yv.y) + (yv.z + yv.w);
        s += dppf<DPP_XOR1>(s);
        s += dppf<DPP_XOR2>(s);
        s += dppf<DPP_XOR7>(s);
        if (lane == 0) yp[SEQ - 1] = 1.f / (1.f + __expf(-(s + b0v)));
    }
#undef STEP
}

extern "C" void kernel_launch(void* const* d_in, const int* in_sizes, int n_in,
                              void* d_out, int out_size, void* d_ws, size_t ws_size,
                              hipStream_t stream) {
    const float* x     = (const float*)d_in[0];
    const float* h0    = (const float*)d_in[1];
    const float* noise = (const float*)d_in[2];
    const float* W_ih  = (const float*)d_in[3];
    const float* W_hh  = (const float*)d_in[4];
    const float* W_hhb = (const float*)d_in[5];
    const float* b_h   = (const float*)d_in[6];
    const float* W     = (const float*)d_in[7];
    const float* bvec  = (const float*)d_in[8];
    const int*   ctx   = (const int*)d_in[9];

    float* y_out = (float*)d_out;                         // (BATCH, SEQ)
    float* h_out = (float*)d_out + (size_t)BATCH * SEQ;   // (BATCH, SEQ, HID)

    rnn_kernel<<<dim3(BATCH), dim3(512), 0, stream>>>(
        x, h0, noise, W_ih, W_hh, W_hhb, b_h, W, bvec, ctx, h_out, y_out);
}

// Round 3
// 2084.185 us; speedup vs baseline: 1.4415x; 1.0705x over previous
//
#include <hip/hip_runtime.h>
#include <math.h>

#define SEQ   2048
#define BATCH 128
#define HID   256
#define CHUNK_B 80   // 16-float chunk = 64 B data + 16 B pad (bank spread)

typedef float vf2 __attribute__((ext_vector_type(2)));
typedef float vf4 __attribute__((ext_vector_type(4)));

// DPP cross-lane exchange (VALU, no LDS pipe).
#define DPP_XOR1  0xB1   // quad_perm [1,0,3,2]  : lane ^ 1
#define DPP_XOR2  0x4E   // quad_perm [2,3,0,1]  : lane ^ 2
#define DPP_XOR7  0x141  // row_half_mirror      : lane ^ 7
#define DPP_XOR15 0x140  // row_mirror           : lane ^ 15
template<int CTRL>
__device__ __forceinline__ float dppf(float v) {
    return __builtin_bit_cast(float, __builtin_amdgcn_update_dpp(
        0, __builtin_bit_cast(int, v), CTRL, 0xF, 0xF, true));
}

// packed 2xf32 FMA: one instruction, two MACs.
#define PKFMA(acc, a, b) \
    asm("v_pk_fma_f32 %0, %1, %2, %0" : "+v"(acc) : "v"(a), "v"(b))

// LDS-visibility-only barrier (no vmcnt drain: global loads/stores stay in flight).
#define BARRIER() do { asm volatile("s_waitcnt lgkmcnt(0)" ::: "memory"); \
                       __builtin_amdgcn_s_barrier(); } while (0)

// One block per batch row; 512 threads = 8 waves.
// Wave w owns rows [w*32, w*32+32). lane = jg*16+kg: jg=lane>>4 (4 groups of
// 8 rows, j0 = w*32+jg*8), kg=lane&15 (k-chunk [kg*16, kg*16+16)).
// Per step/lane: 4x ds_read_b128 (chunk-padded layout, <=2-way banks = free),
// 64 v_pk_fma_f32 (128 MACs), kg-reduce in DPP only (xor7,xor15 plain; xor1,
// xor2 keep-half; bit2 select) -> lane holds row j0+(lane&7) (dup on bit3).
// h_out store + y-projection + y-finalize all deferred to the next step's
// ds_read-latency shadow (after the barrier). One lgkm-only barrier/step.
__global__ __launch_bounds__(512, 2) void rnn_kernel(
    const float* __restrict__ x,      // (SEQ, BATCH)
    const float* __restrict__ h0,     // (BATCH, HID)
    const float* __restrict__ noise,  // (SEQ, BATCH, HID)
    const float* __restrict__ W_ih,   // (HID, 1)
    const float* __restrict__ W_hh,   // (HID, HID)
    const float* __restrict__ W_hhb,  // (HID, HID)
    const float* __restrict__ b_h,    // (HID)
    const float* __restrict__ Wy,     // (OUT, HID) -> row 0
    const float* __restrict__ by,     // (OUT)
    const int*   __restrict__ ctx,    // scalar
    float* __restrict__ h_out,        // (BATCH, SEQ, HID)
    float* __restrict__ y_out)        // (BATCH, SEQ)
{
    const int b    = blockIdx.x;
    const int tid  = threadIdx.x;
    const int w    = tid >> 6;
    const int lane = tid & 63;
    const int jg   = lane >> 4;        // 0..3
    const int kg   = lane & 15;        // 0..15
    const int j0   = w * 32 + jg * 8;
    const int jres = j0 + (lane & 7);  // row this lane holds after reduce
    const bool wr  = (lane & 8) == 0;  // writer (bit3 duplicates)

    __shared__ __align__(16) char  hbuf[2][16 * CHUNK_B];
    __shared__ __align__(16) float ywave[2][32];

    int iv = *ctx;
    float c = (iv > 1000000 || iv < -1000000) ? __int_as_float(iv) : (float)iv;

    // One-time: W_eff slice (8 rows x 16 cols) as 64 float2 in registers.
    vf2 wreg2[8][8];
    #pragma unroll
    for (int e = 0; e < 8; ++e) {
        const vf4* wrp  = (const vf4*)&W_hh [(j0 + e) * HID + kg * 16];
        const vf4* wrbp = (const vf4*)&W_hhb[(j0 + e) * HID + kg * 16];
        #pragma unroll
        for (int q = 0; q < 4; ++q) {
            vf4 av = wrp[q], bv = wrbp[q];
            vf2 lo, hi;
            lo.x = av.x + c * bv.x;  lo.y = av.y + c * bv.y;
            hi.x = av.z + c * bv.z;  hi.y = av.w + c * bv.w;
            wreg2[e][2 * q]     = lo;
            wreg2[e][2 * q + 1] = hi;
        }
    }

    const float win = W_ih[jres];
    const float bh  = b_h[jres];
    const float w0  = Wy[jres];        // row 0 of W
    const float b0v = by[0];

    // Initial h into padded layout: logical j -> byte (j>>4)*80 + (j&15)*4.
    if (tid < HID)
        *(float*)&hbuf[0][(tid >> 4) * CHUNK_B + (tid & 15) * 4] = h0[b * HID + tid];

    // Precomputed LDS addresses (no per-step address math).
    const char* hrpA = &hbuf[0][kg * CHUNK_B];
    const char* hrpB = &hbuf[1][kg * CHUNK_B];
    const int   wbyte = (jres >> 4) * CHUNK_B + (jres & 15) * 4;
    float* wpA = (float*)&hbuf[0][wbyte];
    float* wpB = (float*)&hbuf[1][wbyte];

    // Depth-2 prefetch of x / noise.
    float x_next  = x[b];
    float n_next  = noise[(size_t)b * HID + jres];
    float x_next2 = x[BATCH + b];
    float n_next2 = noise[((size_t)BATCH + b) * HID + jres];
    const float* xp = x + 2 * BATCH + b;
    const float* np = noise + ((size_t)2 * BATCH + b) * HID + jres;

    float* hout_b = h_out + (size_t)b * SEQ * HID;
    float* yp     = y_out + (size_t)b * SEQ;
    int    ho     = 0;
    float  hn_prev = 0.f;

    __syncthreads();

#define STEP(HRP, WPT, DO_PREV, YWW, DO_FIN, YWR, FINW, TFIN, ADV)           \
  {                                                                          \
    /* critical-path LDS reads first */                                      \
    vf4 h40 = *(const vf4*)((HRP) + 0);                                      \
    vf4 h41 = *(const vf4*)((HRP) + 16);                                     \
    vf4 h42 = *(const vf4*)((HRP) + 32);                                     \
    vf4 h43 = *(const vf4*)((HRP) + 48);                                     \
    const float x_t = x_next, n_t = n_next;                                  \
    x_next = x_next2;  n_next = n_next2;                                     \
    x_next2 = *xp;     n_next2 = *np;                                        \
    if (ADV) { xp += BATCH; np += (size_t)BATCH * HID; }                     \
    /* deferred work for h(T-1): runs in the ds_read latency shadow */       \
    if (DO_PREV) {                                                           \
      if (wr) hout_b[ho + jres] = hn_prev;                                   \
      float qy = wr ? hn_prev * w0 : 0.f;                                    \
      qy += dppf<DPP_XOR1>(qy);                                              \
      qy += dppf<DPP_XOR2>(qy);                                              \
      qy += dppf<DPP_XOR7>(qy);                                              \
      qy += dppf<DPP_XOR15>(qy);                                             \
      if ((lane & 15) == 0) (YWW)[w * 4 + jg] = qy;                          \
      ho += HID;                                                             \
    }                                                                        \
    if (DO_FIN && w == (FINW)) {   /* finalize y[T-2] (race-free by bar) */  \
      vf4 yv = *(const vf4*)&(YWR)[(lane & 7) * 4];                          \
      float s = (yv.x + yv.y) + (yv.z + yv.w);                               \
      s += dppf<DPP_XOR1>(s);                                                \
      s += dppf<DPP_XOR2>(s);                                                \
      s += dppf<DPP_XOR7>(s);                                                \
      if (lane == 0)                                                         \
        yp[TFIN] = __builtin_amdgcn_rcpf(1.f + __expf(-(s + b0v)));          \
    }                                                                        \
    /* 128 MACs as 64 pk_fma, grouped by load for fine lgkm waits */         \
    vf2 acc[8];                                                              \
    _Pragma("unroll")                                                        \
    for (int e = 0; e < 8; ++e) acc[e] = (vf2)0.f;                           \
    { vf2 ha = h40.xy, hb = h40.zw;                                          \
      _Pragma("unroll")                                                      \
      for (int e = 0; e < 8; ++e) { PKFMA(acc[e], ha, wreg2[e][0]);          \
                                    PKFMA(acc[e], hb, wreg2[e][1]); } }      \
    { vf2 ha = h41.xy, hb = h41.zw;                                          \
      _Pragma("unroll")                                                      \
      for (int e = 0; e < 8; ++e) { PKFMA(acc[e], ha, wreg2[e][2]);          \
                                    PKFMA(acc[e], hb, wreg2[e][3]); } }      \
    { vf2 ha = h42.xy, hb = h42.zw;                                          \
      _Pragma("unroll")                                                      \
      for (int e = 0; e < 8; ++e) { PKFMA(acc[e], ha, wreg2[e][4]);          \
                                    PKFMA(acc[e], hb, wreg2[e][5]); } }      \
    { vf2 ha = h43.xy, hb = h43.zw;                                          \
      _Pragma("unroll")                                                      \
      for (int e = 0; e < 8; ++e) { PKFMA(acc[e], ha, wreg2[e][6]);          \
                                    PKFMA(acc[e], hb, wreg2[e][7]); } }      \
    /* reduce over kg (lane bits 0-3): plain xor7, xor15; keep-half xor1, */ \
    /* xor2; select bit2 -> lane holds full sum for row j0+(lane&7). */      \
    float p0 = acc[0].x + acc[0].y,  p1 = acc[1].x + acc[1].y;               \
    float p2 = acc[2].x + acc[2].y,  p3 = acc[3].x + acc[3].y;               \
    float p4 = acc[4].x + acc[4].y,  p5 = acc[5].x + acc[5].y;               \
    float p6 = acc[6].x + acc[6].y,  p7 = acc[7].x + acc[7].y;               \
    p0 += dppf<DPP_XOR7>(p0);   p1 += dppf<DPP_XOR7>(p1);                    \
    p2 += dppf<DPP_XOR7>(p2);   p3 += dppf<DPP_XOR7>(p3);                    \
    p4 += dppf<DPP_XOR7>(p4);   p5 += dppf<DPP_XOR7>(p5);                    \
    p6 += dppf<DPP_XOR7>(p6);   p7 += dppf<DPP_XOR7>(p7);                    \
    p0 += dppf<DPP_XOR15>(p0);  p1 += dppf<DPP_XOR15>(p1);                   \
    p2 += dppf<DPP_XOR15>(p2);  p3 += dppf<DPP_XOR15>(p3);                   \
    p4 += dppf<DPP_XOR15>(p4);  p5 += dppf<DPP_XOR15>(p5);                   \
    p6 += dppf<DPP_XOR15>(p6);  p7 += dppf<DPP_XOR15>(p7);                   \
    const bool bb0 = (lane & 1), bb1 = (lane & 2), bb2 = (lane & 4);         \
    float q0 = (bb0 ? p1 : p0) + dppf<DPP_XOR1>(bb0 ? p0 : p1);              \
    float q1 = (bb0 ? p3 : p2) + dppf<DPP_XOR1>(bb0 ? p2 : p3);              \
    float q2 = (bb0 ? p5 : p4) + dppf<DPP_XOR1>(bb0 ? p4 : p5);              \
    float q3 = (bb0 ? p7 : p6) + dppf<DPP_XOR1>(bb0 ? p6 : p7);              \
    float r0 = (bb1 ? q1 : q0) + dppf<DPP_XOR2>(bb1 ? q0 : q1);              \
    float r1 = (bb1 ? q3 : q2) + dppf<DPP_XOR2>(bb1 ? q2 : q3);              \
    float r  = bb2 ? r1 : r0;                                                \
    float z  = fmaf(x_t, win, r) + bh;                                       \
    float ex = __expf(2.f * z);          /* tanh(z) = 1 - 2/(e^{2z}+1) */    \
    float hn = fmaf(-2.f, __builtin_amdgcn_rcpf(ex + 1.f), 1.f) + n_t;       \
    if (wr) *(WPT) = hn;                                                     \
    hn_prev = hn;                                                            \
    BARRIER();                                                               \
  }

    // step 0 (even): A->B, nothing deferred yet.
    STEP(hrpA, wpB, 0, ywave[1], 0, ywave[0], 7, 0, 1)
    // step 1 (odd): B->A, defer h0 store + qy -> ywave[0].
    STEP(hrpB, wpA, 1, ywave[0], 0, ywave[1], 6, 0, 1)

    for (int t = 2; t < SEQ; t += 2) {
        STEP(hrpA, wpB, 1, ywave[1], 1, ywave[0], 7, t - 2, (t + 3 < SEQ))
        STEP(hrpB, wpA, 1, ywave[0], 1, ywave[1], 6, t - 1, (t + 4 < SEQ))
    }

    // Epilogue: hn_prev = h[SEQ-1]; pending y[SEQ-2] (ywave[0]) and y[SEQ-1].
    if (wr) hout_b[ho + jres] = hn_prev;
    {
        float qy = wr ? hn_prev * w0 : 0.f;
        qy += dppf<DPP_XOR1>(qy);
        qy += dppf<DPP_XOR2>(qy);
        qy += dppf<DPP_XOR7>(qy);
        qy += dppf<DPP_XOR15>(qy);
        if ((lane & 15) == 0) ywave[1][w * 4 + jg] = qy;
    }
    if (w == 7) {
        vf4 yv = *(const vf4*)&ywave[0][(lane & 7) * 4];
        float s = (yv.x + yv.y) + (yv.z + yv.w);
        s += dppf<DPP_XOR1>(s);
        s += dppf<DPP_XOR2>(s);
        s += dppf<DPP_XOR7>(s);
        if (lane == 0) yp[SEQ - 2] = __builtin_amdgcn_rcpf(1.f + __expf(-(s + b0v)));
    }
    BARRIER();
    if (w == 6) {
        vf4 yv = *(const vf4*)&ywave[1][(lane & 7) * 4];
        float s = (yv.x + yv.y) + (yv.z + yv.w);
        s += dppf<DPP_XOR1>(s);
        s += dppf<DPP_XOR2>(s);
        s += dppf<DPP_XOR7>(s);
        if (lane == 0) yp[SEQ - 1] = __builtin_amdgcn_rcpf(1.f + __expf(-(s + b0v)));
    }
#undef STEP
}

extern "C" void kernel_launch(void* const* d_in, const int* in_sizes, int n_in,
                              void* d_out, int out_size, void* d_ws, size_t ws_size,
                              hipStream_t stream) {
    const float* x     = (const float*)d_in[0];
    const float* h0    = (const float*)d_in[1];
    const float* noise = (const float*)d_in[2];
    const float* W_ih  = (const float*)d_in[3];
    const float* W_hh  = (const float*)d_in[4];
    const float* W_hhb = (const float*)d_in[5];
    const float* b_h   = (const float*)d_in[6];
    const float* W     = (const float*)d_in[7];
    const float* bvec  = (const float*)d_in[8];
    const int*   ctx   = (const int*)d_in[9];

    float* y_out = (float*)d_out;                         // (BATCH, SEQ)
    float* h_out = (float*)d_out + (size_t)BATCH * SEQ;   // (BATCH, SEQ, HID)

    rnn_kernel<<<dim3(BATCH), dim3(512), 0, stream>>>(
        x, h0, noise, W_ih, W_hh, W_hhb, b_h, W, bvec, ctx, h_out, y_out);
}